// Round 11
// baseline (349.235 us; speedup 1.0000x reference)
//
#include <hip/hip_runtime.h>
#include <hip/hip_bf16.h>

#define M_DIM 8192
#define N_DIM 4096
#define K_DIM 4096
#define NT 128   // K-tiles of BK=32

typedef __bf16 bf16x8 __attribute__((ext_vector_type(8)));
typedef float f32x4 __attribute__((ext_vector_type(4)));
typedef unsigned short ushort8v __attribute__((ext_vector_type(8)));

typedef const __attribute__((address_space(1))) void gv_t;
typedef __attribute__((address_space(3))) void lv_t;

static __device__ __forceinline__ unsigned short f2bf(float f) {
  unsigned u = __builtin_bit_cast(unsigned, f);
  u += 0x7fffu + ((u >> 16) & 1u);
  return (unsigned short)(u >> 16);
}

// ---------------- pre-pass 1: inverse permutation ----------------
__global__ void k_pinv(const int* __restrict__ ci, int* __restrict__ pinv) {
  int k = blockIdx.x * 256 + threadIdx.x;
  if (k < K_DIM) pinv[ci[k]] = k;
}

// ---------------- pre-pass 2: x fp32 -> bf16 ----------------
__global__ void k_cvt(const float* __restrict__ x, unsigned short* __restrict__ xb) {
  const long n4 = (long)M_DIM * K_DIM / 4;
  for (long i = (long)blockIdx.x * 256 + threadIdx.x; i < n4; i += 2048L * 256) {
    float4 v = *(const float4*)(x + i * 4);
    ushort4 o;
    o.x = f2bf(v.x); o.y = f2bf(v.y); o.z = f2bf(v.z); o.w = f2bf(v.w);
    *(ushort4*)(xb + i * 4) = o;
  }
}

// ---------------- pre-pass 3: dequant + permute + transpose ----------------
__global__ void k_w2t(const int* __restrict__ w, const float* __restrict__ scales,
                      const int* __restrict__ pinv, unsigned short* __restrict__ w2t) {
  __shared__ int tile[64 * 68];
  __shared__ int grp[64];
  __shared__ int krow[64];
  const int n0 = blockIdx.x * 64;
  const int c0 = blockIdx.y * 64;
  const int t = threadIdx.x;
  if (t < 64) {
    int kk = pinv[c0 + t];
    krow[t] = kk;
    grp[t] = kk >> 7;
  }
  __syncthreads();
  {
    const int ci = t >> 2, q = t & 3;
    const int kk = krow[ci];
    const int* src = w + (long)kk * N_DIM + n0 + q * 16;
#pragma unroll
    for (int j = 0; j < 4; ++j) {
      int4 v = *(const int4*)(src + j * 4);
      *(int4*)&tile[ci * 68 + q * 16 + j * 4] = v;
    }
  }
  __syncthreads();
  {
    const int nj = t >> 2, cq = t & 3;
    const int n = n0 + nj;
    unsigned short outv[16];
#pragma unroll
    for (int i = 0; i < 16; ++i) {
      int cii = cq * 16 + i;
      float f = (float)tile[cii * 68 + nj] * scales[grp[cii] * N_DIM + n];
      outv[i] = f2bf(f);
    }
    unsigned short* dst = w2t + (long)n * K_DIM + c0 + cq * 16;
    *(ushort8v*)(dst)     = *(ushort8v*)&outv[0];
    *(ushort8v*)(dst + 8) = *(ushort8v*)&outv[8];
  }
}

// ---------------- main GEMM: 128x256 tile, BK=32, 4 waves, 3-buf distance-2 ----------------
// 2 blocks/CU co-resident (72 KiB LDS, ~240 regs/wave -> 2 waves/SIMD from DIFFERENT
// blocks): when one block stalls at barrier/vmcnt the other issues MFMA (m97 regime).
// Buffers: 3 x 24 KiB (A[128x32] @0, B[256x32] @8192). 16x16x32 MFMA (r6-proven; 32x32
// regressed in r8-r10). Swizzle involution addr^(((addr>>7)&7)<<4) on both sides (r3).
// Per tile t: Pa {RD A0-3+B0-3; stage t+2 (6 GL); bar; lgkm0; 16 MFMA; bar}
//             Pb {RD A4-7; bar; lgkm0; 16 MFMA; gate; bar}
// Gates FIFO-audited: t<126 -> vmcnt(6) (drains t+1, issued ~4 phases earlier, never
// hot); t==126 -> vmcnt(0); t==127 none.
#define GL(s, d) __builtin_amdgcn_global_load_lds((gv_t*)(s), (lv_t*)(d), 16, 0, 0)
#define BAR_IN() do { __builtin_amdgcn_s_barrier(); \
  asm volatile("s_waitcnt lgkmcnt(0)" ::: "memory"); \
  __builtin_amdgcn_sched_barrier(0); } while(0)
#define BAR_OUT() do { __builtin_amdgcn_sched_barrier(0); \
  __builtin_amdgcn_s_barrier(); __builtin_amdgcn_sched_barrier(0); } while(0)
#define MFMA16(o) do { \
  _Pragma("unroll") for (int mi = 0; mi < 4; ++mi) \
  _Pragma("unroll") for (int ni = 0; ni < 4; ++ni) \
    acc[(o)+mi][ni] = __builtin_amdgcn_mfma_f32_16x16x32_bf16(af[mi], bf[ni], acc[(o)+mi][ni], 0, 0, 0); \
  } while(0)

__global__ __launch_bounds__(256, 2) void k_gemm(const unsigned short* __restrict__ A,
                                                 const unsigned short* __restrict__ Bt,
                                                 const float* __restrict__ bias,
                                                 float* __restrict__ C) {
  __shared__ __attribute__((aligned(16))) char lds[3 * 24576];   // 72 KiB

  const int bid = blockIdx.x;                    // 1024 blocks, %8==0 -> bijective
  const int swz = (bid & 7) * 128 + (bid >> 3);
  const int by = swz >> 4;                       // 0..63  (M tiles of 128)
  const int bx = swz & 15;                       // 0..15  (N tiles of 256)

  const int tid = threadIdx.x;
  const int l = tid & 63;
  const int w = tid >> 6;        // 0..3 -> B cols w*64..+64; all waves share A rows 0..127
  const int r4 = l & 15;
  const int kb = (l >> 4) << 4;  // 0,16,32,48 bytes within 64B k-row

  // ---- staging sources (pre-swizzled global; LDS dest linear tid*16) ----
  // slot o = tid*16 (+L*4096): logical = o ^ wmask, wmask = ((o>>7)&7)<<4 = ((tid>>3)&7)<<4
  const int wmask = ((tid >> 3) & 7) << 4;
  const int olg = (tid * 16) ^ wmask;
  const int row_s = olg >> 6;                    // 0..63
  const int kb_s = olg & 63;
  const char* srcA = (const char*)A + (size_t)(by * 128 + row_s) * (K_DIM * 2) + kb_s;
  const char* srcB = (const char*)Bt + (size_t)(bx * 256 + row_s) * (K_DIM * 2) + kb_s;
  const int stg16 = tid * 16;

  // ---- fragment read bases (r3-verified): addr = ((row<<6)+kb) ^ ((r4&14)<<3) ----
  const int rmask = (r4 & 14) << 3;
  const int aoff0 = ((r4 << 6) + kb) ^ rmask;              // + mi*1024, rows mi*16+r4
  const int boff0 = (((w * 64 + r4) << 6) + kb) ^ rmask;   // + ni*1024

  f32x4 acc[8][4];
  const f32x4 z = {0.f, 0.f, 0.f, 0.f};
#pragma unroll
  for (int mi = 0; mi < 8; ++mi)
#pragma unroll
    for (int ni = 0; ni < 4; ++ni) acc[mi][ni] = z;

  // ---- prologue: stage tile0 -> buf0, tile1 -> buf1 (6 loads each) ----
#pragma unroll
  for (int tt = 0; tt < 2; ++tt) {
    char* bs = lds + tt * 24576;
    const long ko = (long)tt * 64;
#pragma unroll
    for (int jj = 0; jj < 2; ++jj)
      GL(srcA + ko + jj * 524288, bs + jj * 4096 + stg16);
#pragma unroll
    for (int jj = 0; jj < 4; ++jj)
      GL(srcB + ko + jj * 524288, bs + 8192 + jj * 4096 + stg16);
  }
  asm volatile("s_waitcnt vmcnt(6)" ::: "memory");   // tile 0 landed
  BAR_OUT();

  bf16x8 af[4], bf[4];
  int cur = 0;
  for (int t = 0; t < NT; ++t) {
    char* bc = lds + cur * 24576;
    int s2 = cur + 2; if (s2 >= 3) s2 -= 3;
    char* bs = lds + s2 * 24576;
    const long ko = (long)(t + 2) * 64;

    // ===== Pa: A-lo + B reads; stage t+2; MFMA mi0-3 =====
#pragma unroll
    for (int mi = 0; mi < 4; ++mi)
      af[mi] = *(const bf16x8*)(bc + aoff0 + mi * 1024);
#pragma unroll
    for (int ni = 0; ni < 4; ++ni)
      bf[ni] = *(const bf16x8*)(bc + 8192 + boff0 + ni * 1024);
    if (t + 2 < NT) {
#pragma unroll
      for (int jj = 0; jj < 2; ++jj)
        GL(srcA + ko + jj * 524288, bs + jj * 4096 + stg16);
#pragma unroll
      for (int jj = 0; jj < 4; ++jj)
        GL(srcB + ko + jj * 524288, bs + 8192 + jj * 4096 + stg16);
    }
    BAR_IN();
    __builtin_amdgcn_s_setprio(1); MFMA16(0); __builtin_amdgcn_s_setprio(0);
    BAR_OUT();

    // ===== Pb: A-hi reads; MFMA mi4-7; counted gate =====
#pragma unroll
    for (int mi = 0; mi < 4; ++mi)
      af[mi] = *(const bf16x8*)(bc + aoff0 + (4 + mi) * 1024);
    BAR_IN();
    __builtin_amdgcn_s_setprio(1); MFMA16(4); __builtin_amdgcn_s_setprio(0);
    if (t < NT - 2)       asm volatile("s_waitcnt vmcnt(6)" ::: "memory");
    else if (t == NT - 2) asm volatile("s_waitcnt vmcnt(0)" ::: "memory");
    BAR_OUT();

    cur = cur + 1; if (cur >= 3) cur -= 3;
  }

  // ---- epilogue: C/D layout col=l&15, row=(l>>4)*4+reg ----
  const int row0 = by * 128 + ((l >> 4) << 2);
  const int col0 = bx * 256 + w * 64 + r4;
#pragma unroll
  for (int ni = 0; ni < 4; ++ni) {
    const int col = col0 + ni * 16;
    const float bv = bias[col];
#pragma unroll
    for (int mi = 0; mi < 8; ++mi) {
#pragma unroll
      for (int r = 0; r < 4; ++r)
        C[(size_t)(row0 + mi * 16 + r) * N_DIM + col] = acc[mi][ni][r] + bv;
    }
  }
}

// ---------------- fallback ----------------
__global__ void k_fallback(const float* __restrict__ x, const float* __restrict__ scales,
                           const float* __restrict__ bias, const int* __restrict__ w,
                           const int* __restrict__ ci, float* __restrict__ out) {
  const int n = blockIdx.x * 256 + threadIdx.x;
  const int m0 = blockIdx.y * 32;
  float acc[32];
#pragma unroll
  for (int i = 0; i < 32; ++i) acc[i] = 0.f;
  for (int k = 0; k < K_DIM; ++k) {
    int c = ci[k];
    float wv = (float)w[(long)k * N_DIM + n] * scales[(k >> 7) * N_DIM + n];
#pragma unroll 8
    for (int mm = 0; mm < 32; ++mm)
      acc[mm] += x[(long)(m0 + mm) * K_DIM + c] * wv;
  }
  float bv = bias[n];
  for (int mm = 0; mm < 32; ++mm)
    out[(long)(m0 + mm) * N_DIM + n] = acc[mm] + bv;
}

extern "C" void kernel_launch(void* const* d_in, const int* in_sizes, int n_in,
                              void* d_out, int out_size, void* d_ws, size_t ws_size,
                              hipStream_t stream) {
  const float* x      = (const float*)d_in[0];
  const float* scales = (const float*)d_in[1];
  const float* bias   = (const float*)d_in[2];
  const int*   wq     = (const int*)d_in[3];
  const int*   ci     = (const int*)d_in[4];
  float* out = (float*)d_out;

  const size_t xb_bytes  = (size_t)M_DIM * K_DIM * 2;
  const size_t w2t_bytes = (size_t)N_DIM * K_DIM * 2;
  const size_t need = xb_bytes + w2t_bytes + (size_t)K_DIM * 4;

  if (ws_size < need) {
    k_fallback<<<dim3(N_DIM / 256, M_DIM / 32), 256, 0, stream>>>(x, scales, bias, wq, ci, out);
    return;
  }

  unsigned short* xb  = (unsigned short*)d_ws;
  unsigned short* w2t = (unsigned short*)((char*)d_ws + xb_bytes);
  int* pinv           = (int*)((char*)d_ws + xb_bytes + w2t_bytes);

  k_pinv<<<K_DIM / 256, 256, 0, stream>>>(ci, pinv);
  k_cvt<<<2048, 256, 0, stream>>>(x, xb);
  k_w2t<<<dim3(N_DIM / 64, K_DIM / 64), 256, 0, stream>>>(wq, scales, pinv, w2t);
  k_gemm<<<(M_DIM / 128) * (N_DIM / 256), 256, 0, stream>>>(xb, w2t, bias, out);
}

// Round 12
// 303.253 us; speedup vs baseline: 1.1516x; 1.1516x over previous
//
#include <hip/hip_runtime.h>
#include <hip/hip_bf16.h>

#define M_DIM 8192
#define N_DIM 4096
#define K_DIM 4096
#define NITER 32   // 32 iters x 2 K-tiles(64) = 4096

typedef __bf16 bf16x8 __attribute__((ext_vector_type(8)));
typedef float f32x4 __attribute__((ext_vector_type(4)));
typedef unsigned short ushort8v __attribute__((ext_vector_type(8)));

typedef const __attribute__((address_space(1))) void gv_t;
typedef __attribute__((address_space(3))) void lv_t;

static __device__ __forceinline__ unsigned short f2bf(float f) {
  unsigned u = __builtin_bit_cast(unsigned, f);
  u += 0x7fffu + ((u >> 16) & 1u);
  return (unsigned short)(u >> 16);
}

// ---------------- pre-pass 1: inverse permutation ----------------
__global__ void k_pinv(const int* __restrict__ ci, int* __restrict__ pinv) {
  int k = blockIdx.x * 256 + threadIdx.x;
  if (k < K_DIM) pinv[ci[k]] = k;
}

// ---------------- pre-pass 2: x fp32 -> bf16 ----------------
__global__ void k_cvt(const float* __restrict__ x, unsigned short* __restrict__ xb) {
  const long n4 = (long)M_DIM * K_DIM / 4;
  for (long i = (long)blockIdx.x * 256 + threadIdx.x; i < n4; i += 2048L * 256) {
    float4 v = *(const float4*)(x + i * 4);
    ushort4 o;
    o.x = f2bf(v.x); o.y = f2bf(v.y); o.z = f2bf(v.z); o.w = f2bf(v.w);
    *(ushort4*)(xb + i * 4) = o;
  }
}

// ---------------- pre-pass 3: dequant + permute + transpose ----------------
__global__ void k_w2t(const int* __restrict__ w, const float* __restrict__ scales,
                      const int* __restrict__ pinv, unsigned short* __restrict__ w2t) {
  __shared__ int tile[64 * 68];
  __shared__ int grp[64];
  __shared__ int krow[64];
  const int n0 = blockIdx.x * 64;
  const int c0 = blockIdx.y * 64;
  const int t = threadIdx.x;
  if (t < 64) {
    int kk = pinv[c0 + t];
    krow[t] = kk;
    grp[t] = kk >> 7;
  }
  __syncthreads();
  {
    const int ci = t >> 2, q = t & 3;
    const int kk = krow[ci];
    const int* src = w + (long)kk * N_DIM + n0 + q * 16;
#pragma unroll
    for (int j = 0; j < 4; ++j) {
      int4 v = *(const int4*)(src + j * 4);
      *(int4*)&tile[ci * 68 + q * 16 + j * 4] = v;
    }
  }
  __syncthreads();
  {
    const int nj = t >> 2, cq = t & 3;
    const int n = n0 + nj;
    unsigned short outv[16];
#pragma unroll
    for (int i = 0; i < 16; ++i) {
      int cii = cq * 16 + i;
      float f = (float)tile[cii * 68 + nj] * scales[grp[cii] * N_DIM + n];
      outv[i] = f2bf(f);
    }
    unsigned short* dst = w2t + (long)n * K_DIM + c0 + cq * 16;
    *(ushort8v*)(dst)     = *(ushort8v*)&outv[0];
    *(ushort8v*)(dst + 8) = *(ushort8v*)&outv[8];
  }
}

// ---------------- main GEMM: 256x256, BK=64, 8 waves, 8-phase (r6) + COLD GATES ----------------
// r6 structure, re-scheduled staging so every vmcnt gate drains loads >=3.5 phases old
// (r6 gated 1.3-phase-old loads -> in-latency stalls). Chunk j = 64 rows x 128B.
// Writable-from (last read): A1j0,j2@P6 -> stage P7prev; A1j1,j3@P7 -> P0; B1*@P6 -> P7prev/P0;
// B0*@P2 -> P3; A0j0,j2@P2 / j1,j3@P3 -> P4. All of tile-odd needed P4; tile-even needed next-P0.
// GL map: P0{A1j1,A1j3,B1j2,B1j3} P3{B0j0,B0j1} P4{A0j0..3,B0j2,B0j3} P7{A1j0,A1j2,B1j0,B1j1}(ko3).
// Gates: P3-end vmcnt(2) [last iter 0]; P7-end vmcnt(4) [last iter skip]. FIFO-audited incl. edges.
#define RD_A4(base) do { const char* _b=(const char*)(base); \
  af[0]=*(const bf16x8*)(_b); af[1]=*(const bf16x8*)(_b+2048); \
  af[2]=*(const bf16x8*)(_b+4096); af[3]=*(const bf16x8*)(_b+6144); } while(0)
#define RD_B4(base) do { const char* _b=(const char*)(base); \
  bf[0]=*(const bf16x8*)(_b); bf[1]=*(const bf16x8*)(_b+2048); \
  bf[2]=*(const bf16x8*)(_b+4096); bf[3]=*(const bf16x8*)(_b+6144); } while(0)
#define MFMA16(o) do { \
  _Pragma("unroll") for (int mi = 0; mi < 4; ++mi) \
  _Pragma("unroll") for (int ni = 0; ni < 4; ++ni) \
    acc[(o)+mi][ni] = __builtin_amdgcn_mfma_f32_16x16x32_bf16(af[mi], bf[ni], acc[(o)+mi][ni], 0, 0, 0); \
  } while(0)
#define GL(s, d) __builtin_amdgcn_global_load_lds((gv_t*)(s), (lv_t*)(d), 16, 0, 0)
#define BAR_IN() do { __builtin_amdgcn_s_barrier(); \
  asm volatile("s_waitcnt lgkmcnt(0)" ::: "memory"); \
  __builtin_amdgcn_sched_barrier(0); } while(0)
#define BAR_OUT() do { __builtin_amdgcn_sched_barrier(0); \
  __builtin_amdgcn_s_barrier(); __builtin_amdgcn_sched_barrier(0); } while(0)

__global__ __launch_bounds__(512, 2) void k_gemm(const unsigned short* __restrict__ A,
                                                 const unsigned short* __restrict__ Bt,
                                                 const float* __restrict__ bias,
                                                 float* __restrict__ C) {
  __shared__ __attribute__((aligned(16))) char lds[131072];   // 128 KiB
  char* A0 = lds;             // buf0 A (32K), chunks j at +j*8192
  char* B0 = lds + 32768;
  char* A1 = lds + 65536;
  char* B1 = lds + 98304;

  const int bid = blockIdx.x;                  // 512 blocks, %8==0 -> bijective
  const int swz = (bid & 7) * 64 + (bid >> 3);
  const int by = swz >> 4;                     // 0..31
  const int bx = swz & 15;                     // 0..15

  const int tid = threadIdx.x;
  const int l = tid & 63;
  const int w = tid >> 6;
  const int wr = w >> 2;        // 0..1
  const int wc = w & 3;         // 0..3
  const int r4 = l & 15;
  const int kb = (l >> 4) << 4;               // 0,16,32,48

  // staging sources (pre-swizzled; LDS dest linear). Rows of 128B; chunk j = rows [64j,64j+64).
  const int wmask = ((tid >> 3) & 7) << 4;
  const int kbo = ((tid & 7) * 16) ^ wmask;
  const char* srcA = (const char*)A + (size_t)(by * 256 + (tid >> 3)) * (K_DIM * 2) + kbo;
  const char* srcB = (const char*)Bt + (size_t)(bx * 256 + (tid >> 3)) * (K_DIM * 2) + kbo;
  const int stgoff = tid * 16;

  // fragment read bases: addr = ((row<<7)+kb) ^ ((row&7)<<4); kh1 = ^64; mi-hi = +8192
  const int R0A = wr * 128 + r4;
  const int R0B = wc * 64 + r4;
  const int aoff = ((R0A << 7) + kb) ^ ((R0A & 7) << 4);
  const int boff = ((R0B << 7) + kb) ^ ((R0B & 7) << 4);

  f32x4 acc[8][4];
  const f32x4 z = {0.f, 0.f, 0.f, 0.f};
#pragma unroll
  for (int mi = 0; mi < 8; ++mi)
#pragma unroll
    for (int ni = 0; ni < 4; ++ni) acc[mi][ni] = z;

  // ---- prologue: tile0 full (8 GL) + tile1 group1 {A1j0,A1j2,B1j0,B1j1} (4 GL) ----
#pragma unroll
  for (int j = 0; j < 4; ++j) GL(srcA + j * 524288, A0 + j * 8192 + stgoff);
#pragma unroll
  for (int j = 0; j < 4; ++j) GL(srcB + j * 524288, B0 + j * 8192 + stgoff);
  GL(srcA + 128 + 0 * 524288, A1 + 0 * 8192 + stgoff);
  GL(srcA + 128 + 2 * 524288, A1 + 2 * 8192 + stgoff);
  GL(srcB + 128 + 0 * 524288, B1 + 0 * 8192 + stgoff);
  GL(srcB + 128 + 1 * 524288, B1 + 1 * 8192 + stgoff);
  asm volatile("s_waitcnt vmcnt(4)" ::: "memory");   // tile0 landed; group1 in flight
  BAR_OUT();

  bf16x8 af[4], bf[4];

  for (int J = 0; J < NITER; ++J) {
    const bool nl = (J < NITER - 1);
    const long ko1 = (long)(2 * J + 1) * 128;   // tile 2J+1 byte-col
    const long ko2 = ko1 + 128;                 // tile 2J+2
    const long ko3 = ko1 + 256;                 // tile 2J+3

    // ===== P0: tile2J kh0 lo; stage tile2J+1 group2 {A1j1,A1j3,B1j2,B1j3} =====
    RD_A4(A0 + aoff);
    RD_B4(B0 + boff);
    GL(srcA + ko1 + 1 * 524288, A1 + 1 * 8192 + stgoff);
    GL(srcA + ko1 + 3 * 524288, A1 + 3 * 8192 + stgoff);
    GL(srcB + ko1 + 2 * 524288, B1 + 2 * 8192 + stgoff);
    GL(srcB + ko1 + 3 * 524288, B1 + 3 * 8192 + stgoff);
    BAR_IN();
    __builtin_amdgcn_s_setprio(1); MFMA16(0); __builtin_amdgcn_s_setprio(0);
    BAR_OUT();

    // ===== P1: tile2J kh0 hi =====
    RD_A4(A0 + aoff + 8192);
    BAR_IN();
    __builtin_amdgcn_s_setprio(1); MFMA16(4); __builtin_amdgcn_s_setprio(0);
    BAR_OUT();

    // ===== P2: tile2J kh1 lo =====
    RD_A4(A0 + (aoff ^ 64));
    RD_B4(B0 + (boff ^ 64));
    BAR_IN();
    __builtin_amdgcn_s_setprio(1); MFMA16(0); __builtin_amdgcn_s_setprio(0);
    BAR_OUT();

    // ===== P3: tile2J kh1 hi; stage B0j0,B0j1 (tile2J+2); GATE tile2J+1 =====
    RD_A4(A0 + (aoff ^ 64) + 8192);
    if (nl) {
      GL(srcB + ko2 + 0 * 524288, B0 + 0 * 8192 + stgoff);
      GL(srcB + ko2 + 1 * 524288, B0 + 1 * 8192 + stgoff);
    }
    BAR_IN();
    __builtin_amdgcn_s_setprio(1); MFMA16(4); __builtin_amdgcn_s_setprio(0);
    if (nl) asm volatile("s_waitcnt vmcnt(2)" ::: "memory");   // drains both tile2J+1 batches
    else    asm volatile("s_waitcnt vmcnt(0)" ::: "memory");
    BAR_OUT();

    // ===== P4: tile2J+1 kh0 lo; stage A0j0..3 + B0j2,B0j3 (tile2J+2) =====
    RD_A4(A1 + aoff);
    RD_B4(B1 + boff);
    if (nl) {
      GL(srcA + ko2 + 0 * 524288, A0 + 0 * 8192 + stgoff);
      GL(srcA + ko2 + 1 * 524288, A0 + 1 * 8192 + stgoff);
      GL(srcA + ko2 + 2 * 524288, A0 + 2 * 8192 + stgoff);
      GL(srcA + ko2 + 3 * 524288, A0 + 3 * 8192 + stgoff);
      GL(srcB + ko2 + 2 * 524288, B0 + 2 * 8192 + stgoff);
      GL(srcB + ko2 + 3 * 524288, B0 + 3 * 8192 + stgoff);
    }
    BAR_IN();
    __builtin_amdgcn_s_setprio(1); MFMA16(0); __builtin_amdgcn_s_setprio(0);
    BAR_OUT();

    // ===== P5: tile2J+1 kh0 hi =====
    RD_A4(A1 + aoff + 8192);
    BAR_IN();
    __builtin_amdgcn_s_setprio(1); MFMA16(4); __builtin_amdgcn_s_setprio(0);
    BAR_OUT();

    // ===== P6: tile2J+1 kh1 lo =====
    RD_A4(A1 + (aoff ^ 64));
    RD_B4(B1 + (boff ^ 64));
    BAR_IN();
    __builtin_amdgcn_s_setprio(1); MFMA16(0); __builtin_amdgcn_s_setprio(0);
    BAR_OUT();

    // ===== P7: tile2J+1 kh1 hi; stage tile2J+3 group1; GATE tile2J+2 =====
    RD_A4(A1 + (aoff ^ 64) + 8192);
    if (nl) {
      GL(srcA + ko3 + 0 * 524288, A1 + 0 * 8192 + stgoff);
      GL(srcA + ko3 + 2 * 524288, A1 + 2 * 8192 + stgoff);
      GL(srcB + ko3 + 0 * 524288, B1 + 0 * 8192 + stgoff);
      GL(srcB + ko3 + 1 * 524288, B1 + 1 * 8192 + stgoff);
    }
    BAR_IN();
    __builtin_amdgcn_s_setprio(1); MFMA16(4); __builtin_amdgcn_s_setprio(0);
    if (nl) asm volatile("s_waitcnt vmcnt(4)" ::: "memory");   // drains P3+P4 (tile2J+2)
    BAR_OUT();
  }

  // ---- epilogue: C/D layout col=l&15, row=(l>>4)*4+reg ----
  const int row0 = by * 256 + wr * 128 + ((l >> 4) << 2);
  const int col0 = bx * 256 + wc * 64 + r4;
#pragma unroll
  for (int ni = 0; ni < 4; ++ni) {
    const int col = col0 + ni * 16;
    const float bv = bias[col];
#pragma unroll
    for (int mi = 0; mi < 8; ++mi) {
#pragma unroll
      for (int r = 0; r < 4; ++r)
        C[(size_t)(row0 + mi * 16 + r) * N_DIM + col] = acc[mi][ni][r] + bv;
    }
  }
}

// ---------------- fallback ----------------
__global__ void k_fallback(const float* __restrict__ x, const float* __restrict__ scales,
                           const float* __restrict__ bias, const int* __restrict__ w,
                           const int* __restrict__ ci, float* __restrict__ out) {
  const int n = blockIdx.x * 256 + threadIdx.x;
  const int m0 = blockIdx.y * 32;
  float acc[32];
#pragma unroll
  for (int i = 0; i < 32; ++i) acc[i] = 0.f;
  for (int k = 0; k < K_DIM; ++k) {
    int c = ci[k];
    float wv = (float)w[(long)k * N_DIM + n] * scales[(k >> 7) * N_DIM + n];
#pragma unroll 8
    for (int mm = 0; mm < 32; ++mm)
      acc[mm] += x[(long)(m0 + mm) * K_DIM + c] * wv;
  }
  float bv = bias[n];
  for (int mm = 0; mm < 32; ++mm)
    out[(long)(m0 + mm) * N_DIM + n] = acc[mm] + bv;
}

extern "C" void kernel_launch(void* const* d_in, const int* in_sizes, int n_in,
                              void* d_out, int out_size, void* d_ws, size_t ws_size,
                              hipStream_t stream) {
  const float* x      = (const float*)d_in[0];
  const float* scales = (const float*)d_in[1];
  const float* bias   = (const float*)d_in[2];
  const int*   wq     = (const int*)d_in[3];
  const int*   ci     = (const int*)d_in[4];
  float* out = (float*)d_out;

  const size_t xb_bytes  = (size_t)M_DIM * K_DIM * 2;
  const size_t w2t_bytes = (size_t)N_DIM * K_DIM * 2;
  const size_t need = xb_bytes + w2t_bytes + (size_t)K_DIM * 4;

  if (ws_size < need) {
    k_fallback<<<dim3(N_DIM / 256, M_DIM / 32), 256, 0, stream>>>(x, scales, bias, wq, ci, out);
    return;
  }

  unsigned short* xb  = (unsigned short*)d_ws;
  unsigned short* w2t = (unsigned short*)((char*)d_ws + xb_bytes);
  int* pinv           = (int*)((char*)d_ws + xb_bytes + w2t_bytes);

  k_pinv<<<K_DIM / 256, 256, 0, stream>>>(ci, pinv);
  k_cvt<<<2048, 256, 0, stream>>>(x, xb);
  k_w2t<<<dim3(N_DIM / 64, K_DIM / 64), 256, 0, stream>>>(wq, scales, pinv, w2t);
  k_gemm<<<(M_DIM / 256) * (N_DIM / 256), 512, 0, stream>>>(xb, w2t, bias, out);
}